// Round 5
// baseline (229.891 us; speedup 1.0000x reference)
//
#include <hip/hip_runtime.h>
#include <hip/hip_bf16.h>

typedef short v8s __attribute__((ext_vector_type(8)));
typedef float v4f __attribute__((ext_vector_type(4)));
typedef float v16f __attribute__((ext_vector_type(16)));
typedef float v2f __attribute__((ext_vector_type(2)));

#define LN_EPS 1e-5f
#define EPS_N 1e-3f

__device__ __forceinline__ unsigned short f2bf(float f) {
    __hip_bfloat16 h = __float2bfloat16(f);
    return __builtin_bit_cast(unsigned short, h);
}
__device__ __forceinline__ unsigned int pk2(float a, float b) {
    return (unsigned)f2bf(a) | ((unsigned)f2bf(b) << 16);
}

// ---------------------------------------------------------------------------
// Fragment-linear layouts (element index, 2B elems):
//   a_f/b_f:  ((tile*8 + kb)*64 + lane)*8 + e   tile=R>>5 (R=r*32+h), lane=half*32+(R&31),
//             k = kb*16 + half*8 + e
//   w_out_f:  ((t*4 + zq)*64 + lane)*8 + e8     t=k2''>>4, zq=zh*2+e, lane=half*32+l31,
//             k2'' = t*16 + half*8 + e8, z = zh*64 + 2*l31 + e   (z-interleaved!)
//             (k2'' = (h/4)*128 + k*4 + (h%4))
// ---------------------------------------------------------------------------

__global__ __launch_bounds__(256) void k0_prep(
    const float* __restrict__ mask,
    const float* __restrict__ w1, const float* __restrict__ w2,
    const float* __restrict__ w_out,
    unsigned short* __restrict__ wt,
    unsigned short* __restrict__ w_out_f,
    float* __restrict__ inv_norm) {
    const int b = blockIdx.x, t = threadIdx.x;
    float acc = 0.f;
    for (int s = 0; s < 128; ++s)
        acc += mask[s * 256 + b] * mask[s * 256 + t];
    inv_norm[b * 256 + t] = 1.0f / (EPS_N + acc);
    // w_out_f in fragment-linear order with z-interleave
    for (int e2 = 0; e2 < 2; ++e2) {
        const int d = b * 512 + e2 * 256 + t;
        const int e8 = d & 7;
        const int lane = (d >> 3) & 63;
        const int l31v = lane & 31, halfv = lane >> 5;
        const int zq = (d >> 9) & 3, tt = d >> 11;
        const int zh = zq >> 1, ee = zq & 1;
        const int k2 = tt * 16 + halfv * 8 + e8;
        const int z = zh * 64 + 2 * l31v + ee;
        const int h = (k2 >> 7) * 4 + (k2 & 3);
        const int k = (k2 >> 2) & 31;
        w_out_f[d] = f2bf(w_out[(h * 32 + k) * 128 + z]);
    }
    if (b == 0) {
        for (int e = t; e < 16384; e += 256) {
            int h2 = e >> 8, c = e & 255;
            float v = (h2 < 32) ? w1[c * 32 + h2] : w2[c * 32 + (h2 - 32)];
            wt[e] = f2bf(v);
        }
    }
}

// ---------------------------------------------------------------------------
// k1: WG = (r, s-quarter): 32 s-rows, 4 waves x 8 rows. LN + MFMA 32x64x256,
// epilogue (+bias)*mask -> a_f/b_f fragment-linear. 1024 WGs, 4 WGs/CU.
// ---------------------------------------------------------------------------
__global__ __launch_bounds__(256, 4) void k1_lnproj(
    const float* __restrict__ m, const float* __restrict__ mask,
    const float* __restrict__ ln_w, const float* __restrict__ ln_b,
    const float* __restrict__ b1, const float* __restrict__ b2,
    const unsigned short* __restrict__ wt,
    unsigned short* __restrict__ a_f, unsigned short* __restrict__ b_f) {
    __shared__ unsigned short mh[32 * 256];   // 16 KB, chunk-swizzled
    const int r = blockIdx.x, sq = blockIdx.y;
    const int tid = threadIdx.x;
    const int w = tid >> 6, l = tid & 63;
    const int quad = l >> 4, l15 = l & 15;

    const float4 lwv = *(const float4*)(ln_w + l * 4);
    const float4 lbv = *(const float4*)(ln_b + l * 4);

    // LN: wave w owns local rows w*8 .. w*8+7; prefetch all 8 first
    const int sg0 = sq * 32 + w * 8;
    float4 v[8];
    #pragma unroll
    for (int it = 0; it < 8; ++it)
        v[it] = *(const float4*)(m + (size_t)((sg0 + it) * 256 + r) * 256 + (l << 2));
    #pragma unroll
    for (int it = 0; it < 8; ++it) {
        const float4 x = v[it];
        float sum = x.x + x.y + x.z + x.w;
        float sq2 = x.x * x.x + x.y * x.y + x.z * x.z + x.w * x.w;
        for (int off = 32; off; off >>= 1) {
            sum += __shfl_xor(sum, off);
            sq2 += __shfl_xor(sq2, off);
        }
        const float mu   = sum * (1.f / 256.f);
        const float var  = sq2 * (1.f / 256.f) - mu * mu;
        const float rstd = rsqrtf(var + LN_EPS);
        const unsigned int p0 = pk2((x.x - mu) * rstd * lwv.x + lbv.x,
                                    (x.y - mu) * rstd * lwv.y + lbv.y);
        const unsigned int p1 = pk2((x.z - mu) * rstd * lwv.z + lbv.z,
                                    (x.w - mu) * rstd * lwv.w + lbv.w);
        const int sl = w * 8 + it;
        const int addr = sl * 256 + (((l >> 1) ^ (sl & 31)) << 3) + ((l & 1) << 2);
        *(uint2*)(&mh[addr]) = make_uint2(p0, p1);
    }
    __syncthreads();

    // MFMA: wave w -> m-tile mt=w>>1 (16 rows), n-half nh=w&1 (32 h2 cols)
    const int mt = w >> 1, nh = w & 1;
    v4f acc[2];
    const v4f z4 = {0.f, 0.f, 0.f, 0.f};
    acc[0] = z4; acc[1] = z4;

    const int row = mt * 16 + l15;
    #pragma unroll
    for (int kb = 0; kb < 8; ++kb) {
        const v8s af = *(const v8s*)(&mh[row * 256 + (((kb * 4 + quad) ^ (row & 31)) << 3)]);
        #pragma unroll
        for (int tn = 0; tn < 2; ++tn) {
            const v8s bf = *(const v8s*)(wt + (nh * 32 + tn * 16 + l15) * 256 + kb * 32 + quad * 8);
            acc[tn] = __builtin_amdgcn_mfma_f32_16x16x32_bf16(af, bf, acc[tn], 0, 0, 0);
        }
    }

    // epilogue
    const int s0 = sq * 32 + mt * 16 + quad * 4;
    const int kb_s = s0 >> 4, half_s = (s0 >> 3) & 1, e0 = s0 & 7;
    float mk[4];
    #pragma unroll
    for (int u = 0; u < 4; ++u) mk[u] = mask[(s0 + u) * 256 + r];
    #pragma unroll
    for (int tn = 0; tn < 2; ++tn) {
        const int h2 = nh * 32 + tn * 16 + l15;
        const float bias = (h2 < 32) ? b1[h2] : b2[h2 - 32];
        unsigned short* dst = (h2 < 32) ? a_f : b_f;
        const int h = h2 & 31;
        const v4f f = acc[tn];
        const unsigned int q0 = pk2((f[0] + bias) * mk[0], (f[1] + bias) * mk[1]);
        const unsigned int q1 = pk2((f[2] + bias) * mk[2], (f[3] + bias) * mk[3]);
        const int addr = ((r * 8 + kb_s) * 64 + half_s * 32 + h) * 8 + e0;
        *(uint2*)(dst + addr) = make_uint2(q0, q1);
    }
}

// ---------------------------------------------------------------------------
// k2: 256 WGs x 512 thr, 1 WG/CU. Persistent: wfr (128 VGPR) + A-frags
// (64 VGPR, loaded ONCE). B-frags (64 VGPR) software-pipelined: block k+1's
// loads issue right after stage-2 consumes block k's — latency hides under
// P-write + barrier + stage-3. Epilogue: z-interleaved, one 256B dwordx2 NT
// store per (p,zh).
// ---------------------------------------------------------------------------
__global__ __launch_bounds__(512, 2) void k2_main(
    const unsigned short* __restrict__ a_f,
    const unsigned short* __restrict__ b_f,
    const unsigned short* __restrict__ w_out_f,
    const float* __restrict__ inv_norm,
    const float* __restrict__ b_out,
    float* __restrict__ out) {
    __shared__ __align__(16) unsigned char smem[131072];
    unsigned short* P = (unsigned short*)smem;           // [32][1024] swizzled, 64 KB
    float* red = (float*)(smem + 65536);                 // [8 waves][32 p][32][2], 64 KB

    const int g = blockIdx.x;
    const int ib = g >> 2;
    const int jb0 = (g & 3) * 8;
    const int tid = threadIdx.x;
    const int w = tid >> 6;
    const int l = tid & 63;
    const int l31 = l & 31;
    const int half = l >> 5;

    const int wm = w >> 2, wn = w & 3;     // stage-2 roles
    const int zh = w >> 2, kq = w & 3;     // stage-3 roles

    // persistent w_out fragments (128 VGPR)
    v8s wfr[16][2];
    #pragma unroll
    for (int tl = 0; tl < 16; ++tl) {
        const int t = kq * 16 + tl;
        #pragma unroll
        for (int e = 0; e < 2; ++e)
            wfr[tl][e] = *(const v8s*)(w_out_f + (t * 4 + zh * 2 + e) * 512 + l * 8);
    }
    const float bo0 = b_out[zh * 64 + 2 * l31];
    const float bo1 = b_out[zh * 64 + 2 * l31 + 1];

    // persistent A fragments (64 VGPR, loaded once)
    const unsigned short* ab = a_f + (size_t)(ib * 4 + wm * 2) * 4096 + l * 8;
    v8s aP[16];
    #pragma unroll
    for (int kb = 0; kb < 8; ++kb) {
        aP[kb]     = *(const v8s*)(ab + kb * 512);
        aP[8 + kb] = *(const v8s*)(ab + 4096 + kb * 512);
    }

    // pipelined B fragments (64 VGPR)
    v8s bP[16];
    {
        const unsigned short* bb = b_f + (size_t)(jb0 * 8 + wn * 2) * 4096 + l * 8;
        #pragma unroll
        for (int kb = 0; kb < 8; ++kb) {
            bP[kb]     = *(const v8s*)(bb + kb * 512);
            bP[8 + kb] = *(const v8s*)(bb + 4096 + kb * 512);
        }
    }

    const v16f z16 = {0.f,0.f,0.f,0.f,0.f,0.f,0.f,0.f,0.f,0.f,0.f,0.f,0.f,0.f,0.f,0.f};

    for (int blk = 0; blk < 8; ++blk) {
        const int jb = jb0 + blk;
        // ---- stage 2: all-register MFMA ----
        v16f acc2[2][2];
        acc2[0][0] = z16; acc2[0][1] = z16; acc2[1][0] = z16; acc2[1][1] = z16;
        #pragma unroll
        for (int kb = 0; kb < 8; ++kb) {
            acc2[0][0] = __builtin_amdgcn_mfma_f32_32x32x16_bf16(aP[kb],     bP[kb],     acc2[0][0], 0, 0, 0);
            acc2[0][1] = __builtin_amdgcn_mfma_f32_32x32x16_bf16(aP[kb],     bP[8 + kb], acc2[0][1], 0, 0, 0);
            acc2[1][0] = __builtin_amdgcn_mfma_f32_32x32x16_bf16(aP[8 + kb], bP[kb],     acc2[1][0], 0, 0, 0);
            acc2[1][1] = __builtin_amdgcn_mfma_f32_32x32x16_bf16(aP[8 + kb], bP[8 + kb], acc2[1][1], 0, 0, 0);
        }
        // ---- prefetch next block's B (hides under P-write + barrier + stage3)
        if (blk < 7) {
            const unsigned short* bb = b_f + (size_t)((jb + 1) * 8 + wn * 2) * 4096 + l * 8;
            #pragma unroll
            for (int kb = 0; kb < 8; ++kb) {
                bP[kb]     = *(const v8s*)(bb + kb * 512);
                bP[8 + kb] = *(const v8s*)(bb + 4096 + kb * 512);
            }
        }
        // ---- P write (XOR-swizzled, conflict-free) ----
        #pragma unroll
        for (int mi = 0; mi < 2; ++mi) {
            #pragma unroll
            for (int ni = 0; ni < 2; ++ni) {
                const int p = (2 * wm + mi) * 8 + (2 * wn + ni);
                const int esw = 2 * (p & 15);
                const v16f f = acc2[mi][ni];
                #pragma unroll
                for (int q = 0; q < 4; ++q) {
                    const unsigned int lo = pk2(f[4 * q + 0], f[4 * q + 1]);
                    const unsigned int hi = pk2(f[4 * q + 2], f[4 * q + 3]);
                    const int u8 = (2 * q + half) * 32 + l31;
                    *(uint2*)(P + p * 1024 + ((u8 ^ esw) << 2)) = make_uint2(lo, hi);
                }
            }
        }
        __syncthreads();   // barrier 1: P visible

        // ---- stage 3: LDS A-reads + register B ----
        v16f acc3[2];
        acc3[0] = z16; acc3[1] = z16;
        #pragma unroll
        for (int tl = 0; tl < 16; ++tl) {
            const int t = kq * 16 + tl;
            const int u8 = t * 4 + half * 2;
            const v8s pa = *(const v8s*)(P + l31 * 1024 + ((u8 ^ (2 * (l31 & 15))) << 2));
            acc3[0] = __builtin_amdgcn_mfma_f32_32x32x16_bf16(pa, wfr[tl][0], acc3[0], 0, 0, 0);
            acc3[1] = __builtin_amdgcn_mfma_f32_32x32x16_bf16(pa, wfr[tl][1], acc3[1], 0, 0, 0);
        }
        // ---- partials into disjoint red region ----
        #pragma unroll
        for (int q = 0; q < 4; ++q) {
            #pragma unroll
            for (int u = 0; u < 4; ++u) {
                const int rr = 4 * q + u;
                const int p = u + 8 * q + 4 * half;
                *(float2*)(red + w * 2048 + p * 64 + l31 * 2) =
                    make_float2(acc3[0][rr], acc3[1][rr]);
            }
        }
        __syncthreads();   // barrier 2: red visible + P consumed

        // ---- epilogue: kq-reduction + (+b_out)*inv_norm, 256B NT stores ----
        const int pq = w & 3;
        #pragma unroll
        for (int pi = 0; pi < 4; ++pi) {
            const int p = pq * 8 + half * 4 + pi;
            const int gi = ib * 4 + (p >> 3);
            const int gj = jb * 8 + (p & 7);
            const float inv = inv_norm[gi * 256 + gj];
            float s0 = 0.f, s1 = 0.f;
            #pragma unroll
            for (int k2 = 0; k2 < 4; ++k2) {
                const float2 pr = *(const float2*)(red + (zh * 4 + k2) * 2048 + p * 64 + l31 * 2);
                s0 += pr.x; s1 += pr.y;
            }
            v2f res;
            res.x = (s0 + bo0) * inv;
            res.y = (s1 + bo1) * inv;
            v2f* ob = (v2f*)(out + (size_t)(gi * 256 + gj) * 128 + zh * 64) + l31;
            __builtin_nontemporal_store(res, ob);
        }
    }
}

extern "C" void kernel_launch(void* const* d_in, const int* in_sizes, int n_in,
                              void* d_out, int out_size, void* d_ws, size_t ws_size,
                              hipStream_t stream) {
    const float* m     = (const float*)d_in[0];
    const float* mask  = (const float*)d_in[1];
    const float* ln_w  = (const float*)d_in[2];
    const float* ln_b  = (const float*)d_in[3];
    const float* w1    = (const float*)d_in[4];
    const float* b1    = (const float*)d_in[5];
    const float* w2    = (const float*)d_in[6];
    const float* b2    = (const float*)d_in[7];
    const float* w_out = (const float*)d_in[8];
    const float* b_out = (const float*)d_in[9];
    float* out = (float*)d_out;

    unsigned short* a_f      = (unsigned short*)d_ws;          // 2 MB
    unsigned short* b_f      = a_f + 8192 * 128;               // 2 MB
    unsigned short* w_out_f  = b_f + 8192 * 128;               // 256 KB
    float*          inv_norm = (float*)(w_out_f + 128 * 1024); // 256 KB
    unsigned short* wt       = (unsigned short*)(inv_norm + 65536); // 32 KB

    k0_prep<<<256, 256, 0, stream>>>(mask, w1, w2, w_out, wt, w_out_f, inv_norm);
    k1_lnproj<<<dim3(256, 4), 256, 0, stream>>>(m, mask, ln_w, ln_b, b1, b2, wt, a_f, b_f);
    k2_main<<<256, 512, 0, stream>>>(a_f, b_f, w_out_f, inv_norm, b_out, out);
}

// Round 6
// 195.751 us; speedup vs baseline: 1.1744x; 1.1744x over previous
//
#include <hip/hip_runtime.h>
#include <hip/hip_bf16.h>

typedef short v8s __attribute__((ext_vector_type(8)));
typedef float v4f __attribute__((ext_vector_type(4)));
typedef float v16f __attribute__((ext_vector_type(16)));
typedef float v2f __attribute__((ext_vector_type(2)));

#define LN_EPS 1e-5f
#define EPS_N 1e-3f

__device__ __forceinline__ unsigned short f2bf(float f) {
    __hip_bfloat16 h = __float2bfloat16(f);
    return __builtin_bit_cast(unsigned short, h);
}
__device__ __forceinline__ unsigned int pk2(float a, float b) {
    return (unsigned)f2bf(a) | ((unsigned)f2bf(b) << 16);
}

// ---------------------------------------------------------------------------
// Fragment-linear layouts (element index, 2B elems):
//   a_f/b_f:  ((tile*8 + kb)*64 + lane)*8 + e   tile=R>>5 (R=r*32+h), lane=half*32+(R&31),
//             k = kb*16 + half*8 + e
//   w_out_f:  ((t*4 + zq)*64 + lane)*8 + e8     t=k2''>>4, zq=zh*2+e, lane=half*32+l31,
//             k2'' = t*16 + half*8 + e8, z = zh*64 + 2*l31 + e   (z-interleaved)
//             (k2'' = (h/4)*128 + k*4 + (h%4))
// ---------------------------------------------------------------------------

// k0: all outputs via coalesced READS + scatter WRITES (stores don't stall).
__global__ __launch_bounds__(256) void k0_prep(
    const float* __restrict__ mask,
    const float* __restrict__ w1, const float* __restrict__ w2,
    const float* __restrict__ w_out,
    unsigned short* __restrict__ wt,
    unsigned short* __restrict__ w_out_f,
    float* __restrict__ inv_norm) {
    const int b = blockIdx.x, t = threadIdx.x;
    // wt: coalesced read of w1/w2, scattered write. WGs 0..63, 256 elems each.
    if (b < 32) {
        const int f = b * 256 + t;          // w1 flat: f = c*32+h
        const int c = f >> 5, h = f & 31;
        wt[h * 256 + c] = f2bf(w1[f]);
    } else if (b < 64) {
        const int f = (b - 32) * 256 + t;
        const int c = f >> 5, h = f & 31;
        wt[(32 + h) * 256 + c] = f2bf(w2[f]);
    }
    // w_out_f: coalesced read w_out[f], scatter-write via inverse permutation
    #pragma unroll
    for (int e2 = 0; e2 < 2; ++e2) {
        const int f = b * 512 + e2 * 256 + t;     // f = (h*32+k)*128 + z
        const int h = f >> 12, k = (f >> 7) & 31, z = f & 127;
        const int k2 = (h >> 2) * 128 + k * 4 + (h & 3);
        const int tt = k2 >> 4, halfv = (k2 >> 3) & 1, e8 = k2 & 7;
        const int zhv = z >> 6, l31v = (z & 63) >> 1, ee = z & 1;
        const int d = (((tt * 4 + zhv * 2 + ee) * 2 + halfv) * 32 + l31v) * 8 + e8;
        w_out_f[d] = f2bf(w_out[f]);
    }
    // inv_norm row b, col t; 4-way unrolled for load ILP
    float a0 = 0.f, a1 = 0.f, a2 = 0.f, a3 = 0.f;
    #pragma unroll 4
    for (int s = 0; s < 128; s += 4) {
        a0 += mask[(s + 0) * 256 + b] * mask[(s + 0) * 256 + t];
        a1 += mask[(s + 1) * 256 + b] * mask[(s + 1) * 256 + t];
        a2 += mask[(s + 2) * 256 + b] * mask[(s + 2) * 256 + t];
        a3 += mask[(s + 3) * 256 + b] * mask[(s + 3) * 256 + t];
    }
    inv_norm[b * 256 + t] = 1.0f / (EPS_N + (a0 + a1) + (a2 + a3));
}

// ---------------------------------------------------------------------------
// k1: WG = (r, s-quarter): 32 s-rows, 4 waves x 8 rows. LN + MFMA 32x64x256,
// epilogue (+bias)*mask -> a_f/b_f fragment-linear. 1024 WGs, 4 WGs/CU.
// ---------------------------------------------------------------------------
__global__ __launch_bounds__(256, 4) void k1_lnproj(
    const float* __restrict__ m, const float* __restrict__ mask,
    const float* __restrict__ ln_w, const float* __restrict__ ln_b,
    const float* __restrict__ b1, const float* __restrict__ b2,
    const unsigned short* __restrict__ wt,
    unsigned short* __restrict__ a_f, unsigned short* __restrict__ b_f) {
    __shared__ unsigned short mh[32 * 256];   // 16 KB, chunk-swizzled
    const int r = blockIdx.x, sq = blockIdx.y;
    const int tid = threadIdx.x;
    const int w = tid >> 6, l = tid & 63;
    const int quad = l >> 4, l15 = l & 15;

    const float4 lwv = *(const float4*)(ln_w + l * 4);
    const float4 lbv = *(const float4*)(ln_b + l * 4);

    const int sg0 = sq * 32 + w * 8;
    float4 v[8];
    #pragma unroll
    for (int it = 0; it < 8; ++it)
        v[it] = *(const float4*)(m + (size_t)((sg0 + it) * 256 + r) * 256 + (l << 2));
    #pragma unroll
    for (int it = 0; it < 8; ++it) {
        const float4 x = v[it];
        float sum = x.x + x.y + x.z + x.w;
        float sq2 = x.x * x.x + x.y * x.y + x.z * x.z + x.w * x.w;
        for (int off = 32; off; off >>= 1) {
            sum += __shfl_xor(sum, off);
            sq2 += __shfl_xor(sq2, off);
        }
        const float mu   = sum * (1.f / 256.f);
        const float var  = sq2 * (1.f / 256.f) - mu * mu;
        const float rstd = rsqrtf(var + LN_EPS);
        const unsigned int p0 = pk2((x.x - mu) * rstd * lwv.x + lbv.x,
                                    (x.y - mu) * rstd * lwv.y + lbv.y);
        const unsigned int p1 = pk2((x.z - mu) * rstd * lwv.z + lbv.z,
                                    (x.w - mu) * rstd * lwv.w + lbv.w);
        const int sl = w * 8 + it;
        const int addr = sl * 256 + (((l >> 1) ^ (sl & 31)) << 3) + ((l & 1) << 2);
        *(uint2*)(&mh[addr]) = make_uint2(p0, p1);
    }
    __syncthreads();

    const int mt = w >> 1, nh = w & 1;
    v4f acc[2];
    const v4f z4 = {0.f, 0.f, 0.f, 0.f};
    acc[0] = z4; acc[1] = z4;

    const int row = mt * 16 + l15;
    #pragma unroll
    for (int kb = 0; kb < 8; ++kb) {
        const v8s af = *(const v8s*)(&mh[row * 256 + (((kb * 4 + quad) ^ (row & 31)) << 3)]);
        #pragma unroll
        for (int tn = 0; tn < 2; ++tn) {
            const v8s bf = *(const v8s*)(wt + (nh * 32 + tn * 16 + l15) * 256 + kb * 32 + quad * 8);
            acc[tn] = __builtin_amdgcn_mfma_f32_16x16x32_bf16(af, bf, acc[tn], 0, 0, 0);
        }
    }

    const int s0 = sq * 32 + mt * 16 + quad * 4;
    const int kb_s = s0 >> 4, half_s = (s0 >> 3) & 1, e0 = s0 & 7;
    float mk[4];
    #pragma unroll
    for (int u = 0; u < 4; ++u) mk[u] = mask[(s0 + u) * 256 + r];
    #pragma unroll
    for (int tn = 0; tn < 2; ++tn) {
        const int h2 = nh * 32 + tn * 16 + l15;
        const float bias = (h2 < 32) ? b1[h2] : b2[h2 - 32];
        unsigned short* dst = (h2 < 32) ? a_f : b_f;
        const int h = h2 & 31;
        const v4f f = acc[tn];
        const unsigned int q0 = pk2((f[0] + bias) * mk[0], (f[1] + bias) * mk[1]);
        const unsigned int q1 = pk2((f[2] + bias) * mk[2], (f[3] + bias) * mk[3]);
        const int addr = ((r * 8 + kb_s) * 64 + half_s * 32 + h) * 8 + e0;
        *(uint2*)(dst + addr) = make_uint2(q0, q1);
    }
}

// ---------------------------------------------------------------------------
// k2: 256 WGs x 512 thr, 1 WG/CU. Registers: wfr 128 + aP 64 (persistent),
// acc2/acc3 scoped (shared AGPRs) -> ~256/wave, NO spill. B streamed per
// block into 64 KB LDS via global_load_lds (zero VGPR, async), issued after
// the P-barrier so the DMA hides under stage-3; the end-of-block barrier's
// vmcnt(0) drain guarantees arrival. red = bf16 partials (32 KB).
// LDS: B 64K + P 64K + red 32K = 160 KiB. 2 barriers/block. Epilogue of
// block n-1 runs in block n's stage-2 shadow. NT 256B stores.
// ---------------------------------------------------------------------------
__global__ __launch_bounds__(512, 2) void k2_main(
    const unsigned short* __restrict__ a_f,
    const unsigned short* __restrict__ b_f,
    const unsigned short* __restrict__ w_out_f,
    const float* __restrict__ inv_norm,
    const float* __restrict__ b_out,
    float* __restrict__ out) {
    __shared__ __align__(16) unsigned char smem[163840];
    unsigned short* Bs = (unsigned short*)smem;            // 64 KB: 8 j-tiles
    unsigned short* P  = (unsigned short*)(smem + 65536);  // 64 KB swizzled
    unsigned int*  red = (unsigned int*)(smem + 131072);   // 32 KB bf16-pairs

    const int g = blockIdx.x;
    const int ib = g >> 2, jb0 = (g & 3) * 8;
    const int tid = threadIdx.x, w = tid >> 6, l = tid & 63;
    const int l31 = l & 31, half = l >> 5;
    const int wm = w >> 2, wn = w & 3;     // stage-2 roles
    const int zh = w >> 2, kq = w & 3;     // stage-3 roles

    // persistent w_out fragments (128 VGPR)
    v8s wfr[16][2];
    #pragma unroll
    for (int tl = 0; tl < 16; ++tl) {
        #pragma unroll
        for (int e = 0; e < 2; ++e)
            wfr[tl][e] = *(const v8s*)(w_out_f + ((kq * 16 + tl) * 4 + zh * 2 + e) * 512 + l * 8);
    }
    // persistent A fragments (64 VGPR, WG-invariant)
    v8s aP[16];
    {
        const unsigned short* ab = a_f + (size_t)(ib * 4 + wm * 2) * 4096 + l * 8;
        #pragma unroll
        for (int kb = 0; kb < 8; ++kb) {
            aP[kb]     = *(const v8s*)(ab + kb * 512);
            aP[8 + kb] = *(const v8s*)(ab + 4096 + kb * 512);
        }
    }
    const float bo0 = b_out[zh * 64 + 2 * l31];
    const float bo1 = b_out[zh * 64 + 2 * l31 + 1];

    // async-DMA B for block 0 (8 x 1KB chunks per wave)
    {
        const char* gb = (const char*)b_f + (size_t)jb0 * 65536;
        #pragma unroll
        for (int it = 0; it < 8; ++it) {
            const int c = w * 8 + it;
            __builtin_amdgcn_global_load_lds((const unsigned int*)(gb + c * 1024 + l * 16),
                                             (unsigned int*)((char*)Bs + c * 1024), 16, 0, 0);
        }
    }
    __syncthreads();   // drains B0 DMA (vmcnt(0) before barrier)

    const v16f z16 = {0.f,0.f,0.f,0.f,0.f,0.f,0.f,0.f,0.f,0.f,0.f,0.f,0.f,0.f,0.f,0.f};

    auto epilogue = [&](int jbx) {
        const int pq = w & 3;
        #pragma unroll
        for (int pi = 0; pi < 4; ++pi) {
            const int p = pq * 8 + half * 4 + pi;
            const int gi = ib * 4 + (p >> 3);
            const int gj = jbx * 8 + (p & 7);
            const float inv = inv_norm[gi * 256 + gj];
            float s0 = 0.f, s1 = 0.f;
            #pragma unroll
            for (int kk = 0; kk < 4; ++kk) {
                const unsigned int u = red[(zh * 4 + kk) * 1024 + p * 32 + l31];
                s0 += __builtin_bit_cast(float, u << 16);
                s1 += __builtin_bit_cast(float, u & 0xffff0000u);
            }
            v2f res;
            res.x = (s0 + bo0) * inv;
            res.y = (s1 + bo1) * inv;
            __builtin_nontemporal_store(res,
                (v2f*)(out + (size_t)(gi * 256 + gj) * 128 + zh * 64) + l31);
        }
    };

    int jb_prev = 0;
    for (int blk = 0; blk < 8; ++blk) {
        const int jb = jb0 + blk;
        // ---- stage 2: aP regs x B-LDS ----
        {
            v16f acc2[2][2];
            acc2[0][0] = z16; acc2[0][1] = z16; acc2[1][0] = z16; acc2[1][1] = z16;
            #pragma unroll
            for (int kb = 0; kb < 8; ++kb) {
                const v8s b0 = *(const v8s*)((const char*)Bs + (wn * 2 + 0) * 8192 + kb * 1024 + l * 16);
                const v8s b1 = *(const v8s*)((const char*)Bs + (wn * 2 + 1) * 8192 + kb * 1024 + l * 16);
                acc2[0][0] = __builtin_amdgcn_mfma_f32_32x32x16_bf16(aP[kb],     b0, acc2[0][0], 0, 0, 0);
                acc2[0][1] = __builtin_amdgcn_mfma_f32_32x32x16_bf16(aP[kb],     b1, acc2[0][1], 0, 0, 0);
                acc2[1][0] = __builtin_amdgcn_mfma_f32_32x32x16_bf16(aP[8 + kb], b0, acc2[1][0], 0, 0, 0);
                acc2[1][1] = __builtin_amdgcn_mfma_f32_32x32x16_bf16(aP[8 + kb], b1, acc2[1][1], 0, 0, 0);
            }
            // epilogue(prev) in stage-2's shadow (red stable until after barrier)
            if (blk > 0) epilogue(jb_prev);
            // P write (XOR-swizzled, conflict-free)
            #pragma unroll
            for (int mi = 0; mi < 2; ++mi) {
                #pragma unroll
                for (int ni = 0; ni < 2; ++ni) {
                    const int p = (2 * wm + mi) * 8 + 2 * wn + ni;
                    const int esw = 2 * (p & 15);
                    const v16f f = acc2[mi][ni];
                    #pragma unroll
                    for (int q = 0; q < 4; ++q) {
                        const unsigned int lo = pk2(f[4 * q + 0], f[4 * q + 1]);
                        const unsigned int hi = pk2(f[4 * q + 2], f[4 * q + 3]);
                        const int u8 = (2 * q + half) * 32 + l31;
                        *(uint2*)(P + p * 1024 + ((u8 ^ esw) << 2)) = make_uint2(lo, hi);
                    }
                }
            }
        }
        __syncthreads();   // barrier A: P visible; B region free; epilogue done

        // async-DMA next block's B (hides under stage-3 + red)
        if (blk < 7) {
            const char* gb = (const char*)b_f + (size_t)(jb + 1) * 65536;
            #pragma unroll
            for (int it = 0; it < 8; ++it) {
                const int c = w * 8 + it;
                __builtin_amdgcn_global_load_lds((const unsigned int*)(gb + c * 1024 + l * 16),
                                                 (unsigned int*)((char*)Bs + c * 1024), 16, 0, 0);
            }
        }
        // ---- stage 3: P-LDS x wfr regs ----
        v16f acc3[2];
        acc3[0] = z16; acc3[1] = z16;
        #pragma unroll
        for (int tl = 0; tl < 16; ++tl) {
            const int t = kq * 16 + tl;
            const int u8 = t * 4 + half * 2;
            const v8s pa = *(const v8s*)(P + l31 * 1024 + ((u8 ^ (2 * (l31 & 15))) << 2));
            acc3[0] = __builtin_amdgcn_mfma_f32_32x32x16_bf16(pa, wfr[tl][0], acc3[0], 0, 0, 0);
            acc3[1] = __builtin_amdgcn_mfma_f32_32x32x16_bf16(pa, wfr[tl][1], acc3[1], 0, 0, 0);
        }
        // red write: bf16-packed partials (z-pair per uint)
        #pragma unroll
        for (int q = 0; q < 4; ++q) {
            #pragma unroll
            for (int u = 0; u < 4; ++u) {
                const int rr = 4 * q + u;
                const int p = u + 8 * q + 4 * half;
                red[w * 1024 + p * 32 + l31] = pk2(acc3[0][rr], acc3[1][rr]);
            }
        }
        __syncthreads();   // barrier B: red visible; P consumed; B-DMA drained
        jb_prev = jb;
    }
    epilogue(jb_prev);
}

extern "C" void kernel_launch(void* const* d_in, const int* in_sizes, int n_in,
                              void* d_out, int out_size, void* d_ws, size_t ws_size,
                              hipStream_t stream) {
    const float* m     = (const float*)d_in[0];
    const float* mask  = (const float*)d_in[1];
    const float* ln_w  = (const float*)d_in[2];
    const float* ln_b  = (const float*)d_in[3];
    const float* w1    = (const float*)d_in[4];
    const float* b1    = (const float*)d_in[5];
    const float* w2    = (const float*)d_in[6];
    const float* b2    = (const float*)d_in[7];
    const float* w_out = (const float*)d_in[8];
    const float* b_out = (const float*)d_in[9];
    float* out = (float*)d_out;

    unsigned short* a_f      = (unsigned short*)d_ws;          // 2 MB
    unsigned short* b_f      = a_f + 8192 * 128;               // 2 MB
    unsigned short* w_out_f  = b_f + 8192 * 128;               // 256 KB
    float*          inv_norm = (float*)(w_out_f + 128 * 1024); // 256 KB
    unsigned short* wt       = (unsigned short*)(inv_norm + 65536); // 32 KB

    k0_prep<<<256, 256, 0, stream>>>(mask, w1, w2, w_out, wt, w_out_f, inv_norm);
    k1_lnproj<<<dim3(256, 4), 256, 0, stream>>>(m, mask, ln_w, ln_b, b1, b2, wt, a_f, b_f);
    k2_main<<<256, 512, 0, stream>>>(a_f, b_f, w_out_f, inv_norm, b_out, out);
}